// Round 16
// baseline (820.342 us; speedup 1.0000x reference)
//
#include <hip/hip_runtime.h>
#include <hip/hip_bf16.h>
#include <stdint.h>

// ---------------- problem dims (fixed by setup_inputs) ----------------
#define S_TOK   2048   // tokens (B*S)
#define DMODEL  2048   // D
#define HEXP    512    // H per expert
#define NEXP    32     // E
#define HSH     1024   // shared hidden
#define NPAIR   (S_TOK * 4)   // 8192 (token,expert) pairs, top_k=4
#define NT128   96            // sum ceil(cnt_e/128) <= 8192/128 + 32

// meta layout (ints): 128-row tile table
#define M128_NT  0
#define M128_TE  1
#define M128_TP0 (1 + NT128)
#define M128_TM  (1 + 2 * NT128)
#define META_SIZE (1 + 3 * NT128)

typedef short  s16x8 __attribute__((ext_vector_type(8)));
typedef __bf16 b16x8 __attribute__((ext_vector_type(8)));
typedef float  f32x4 __attribute__((ext_vector_type(4)));

__device__ __forceinline__ f32x4 mfma16x16x32(s16x8 a, s16x8 b, f32x4 c) {
    return __builtin_amdgcn_mfma_f32_16x16x32_bf16(
        __builtin_bit_cast(b16x8, a), __builtin_bit_cast(b16x8, b), c, 0, 0, 0);
}

__device__ __forceinline__ unsigned short f2bf(float f) {
    union { float f; unsigned int u; } v; v.f = f;
    unsigned int u = v.u;
    return (unsigned short)((u + 0x7FFFu + ((u >> 16) & 1u)) >> 16);  // RNE
}

__device__ __forceinline__ float bf2f(unsigned short b) {
    union { unsigned int u; float f; } v; v.u = ((unsigned int)b) << 16;
    return v.f;
}

// async global->LDS, 16B per lane. LDS dest is wave-uniform base + lane*16.
__device__ __forceinline__ void gload16(const unsigned short* g, unsigned short* l) {
    __builtin_amdgcn_global_load_lds(
        (const __attribute__((address_space(1))) void*)(uintptr_t)g,
        (__attribute__((address_space(3))) void*)(uintptr_t)l, 16, 0, 0);
}

// ---- LDS bank swizzle for [row][32-short] GEMM tiles (64B rows) ----
__device__ __forceinline__ int src_col8(int lane) {
    return 8 * ((lane & 3) ^ ((lane >> 3) & 3));
}
__device__ __forceinline__ int frag_ko(int fr, int fq) {
    return 8 * (fq ^ ((fr >> 1) & 3));
}

// ---- bijective XCD-aware block swizzle (grid % 8 == 0) ----
__device__ __forceinline__ int swz8(int bid, int n) {
    return (bid & 7) * (n >> 3) + (bid >> 3);
}

// ---------------- transpose-convert tile: f32 [K][N] -> bf16 [N][K] ----------------
// LDS [64][64] with XOR-swizzled columns: T[n][k ^ key(n)], key(n)=((n>>2)&7)<<3.
// Fill: 16 columnar writers spread over 8 banks (2-way, free). Drain: two 16B-aligned
// uint4 reads at kc^key and (kc+8)^key; global writes 2x16B contiguous.
__device__ __forceinline__ void tconv_tile(const float* __restrict__ s,
                                           unsigned short* __restrict__ d,
                                           const int K, const int N,
                                           const int k0, const int n0,
                                           unsigned short* pool)   // >= 4096 shorts
{
    auto T = (unsigned short (*)[64])pool;
    const int tid = threadIdx.x;
    const int n4 = (tid & 15) * 4;
    const int kr = tid >> 4;
    const int wkey = ((n4 >> 2) & 7) << 3;   // shared by rows n4..n4+3
#pragma unroll
    for (int i = 0; i < 4; ++i) {
        const int k = kr + i * 16;
        const float4 v = *reinterpret_cast<const float4*>(s + (size_t)(k0 + k) * N + n0 + n4);
        const int kk = k ^ wkey;
        T[n4 + 0][kk] = f2bf(v.x);
        T[n4 + 1][kk] = f2bf(v.y);
        T[n4 + 2][kk] = f2bf(v.z);
        T[n4 + 3][kk] = f2bf(v.w);
    }
    __syncthreads();
    const int nw = tid >> 2;
    const int kc = (tid & 3) * 16;
    const int rkey = ((nw >> 2) & 7) << 3;
    const uint4 w0 = *reinterpret_cast<const uint4*>(&T[nw][kc ^ rkey]);
    const uint4 w1 = *reinterpret_cast<const uint4*>(&T[nw][(kc + 8) ^ rkey]);
    unsigned short* o = d + (size_t)(n0 + nw) * K + k0 + kc;   // 16B-aligned
    *reinterpret_cast<uint4*>(o)     = w0;
    *reinterpret_cast<uint4*>(o + 8) = w1;
}

// ---------------- router: logits, sigmoid, biased top-4, coef softmax ----------------
__global__ __launch_bounds__(256)
void router_kernel(const float* __restrict__ x, const float* __restrict__ gate_w,
                   const float* __restrict__ expert_bias,
                   const float* __restrict__ coef_w, const float* __restrict__ coef_b,
                   int* __restrict__ inds, float* __restrict__ scores,
                   float* __restrict__ coefo)
{
    const int t = blockIdx.x;
    const int tid = threadIdx.x;
    const int lane = tid & 63;
    const int wave = tid >> 6;
    const float* xr = x + (size_t)t * DMODEL;

    float xv[32];
#pragma unroll
    for (int j = 0; j < 32; ++j) xv[j] = xr[lane + 64 * j];

    __shared__ float s_logits[NEXP];
    __shared__ float s_coef[2];

    for (int i = 0; i < 8; ++i) {
        const int e = wave * 8 + i;
        const float* wr = gate_w + (size_t)e * DMODEL;
        float p = 0.f;
#pragma unroll
        for (int j = 0; j < 32; ++j) p += xv[j] * wr[lane + 64 * j];
#pragma unroll
        for (int o = 32; o > 0; o >>= 1) p += __shfl_xor(p, o);
        if (lane == 0) s_logits[e] = p;
    }
    if (wave == 0) {
        for (int c = 0; c < 2; ++c) {
            const float* wr = coef_w + (size_t)c * DMODEL;
            float p = 0.f;
#pragma unroll
            for (int j = 0; j < 32; ++j) p += xv[j] * wr[lane + 64 * j];
#pragma unroll
            for (int o = 32; o > 0; o >>= 1) p += __shfl_xor(p, o);
            if (lane == 0) s_coef[c] = p;
        }
    }
    __syncthreads();
    if (tid == 0) {
        float routing[NEXP], biased[NEXP];
        for (int e = 0; e < NEXP; ++e) {
            const float r = 1.f / (1.f + expf(-s_logits[e]));
            routing[e] = r;
            biased[e] = r + expert_bias[e];
        }
        int sel[4]; float sc[4]; float ssum = 0.f;
        for (int k = 0; k < 4; ++k) {
            int best = 0; float bv = -1e30f;
            for (int e = 0; e < NEXP; ++e)
                if (biased[e] > bv) { bv = biased[e]; best = e; }  // strict > = lax.top_k tie rule
            sel[k] = best; sc[k] = routing[best]; ssum += sc[k];
            biased[best] = -1e30f;
        }
        const float inv = 1.f / (ssum + 1e-20f);
        for (int k = 0; k < 4; ++k) {
            inds[t * 4 + k] = sel[k];
            scores[t * 4 + k] = sc[k] * inv;
        }
        const float l0 = s_coef[0] + coef_b[0];
        const float l1 = s_coef[1] + coef_b[1];
        const float m = fmaxf(l0, l1);
        const float e0 = expf(l0 - m), e1 = expf(l1 - m);
        coefo[t * 2 + 0] = e0 / (e0 + e1);
        coefo[t * 2 + 1] = e1 / (e0 + e1);
    }
}

// ---------------- upfront tconv: wg, wu, sg, su + xcast passengers -----------------
// grid 21504 (XCD-swizzled): wg 8192 | wu 8192 | sg 512 | su 512 | xcast 4096
__global__ __launch_bounds__(256)
void tconv_all_kernel(const float* __restrict__ wg, const float* __restrict__ wu,
                      const float* __restrict__ sg, const float* __restrict__ su,
                      unsigned short* __restrict__ W1, unsigned short* __restrict__ W2,
                      unsigned short* __restrict__ sgb, unsigned short* __restrict__ sub_,
                      const float* __restrict__ x, unsigned short* __restrict__ xb)
{
    __shared__ unsigned short pool[64 * 64];
    const int bid = swz8(blockIdx.x, 21504);
    if (bid < 8192) {               // wg [E][2048][512] -> W1 [E][512][2048]
        const int e = bid >> 8, t = bid & 255;
        tconv_tile(wg + (size_t)e * DMODEL * HEXP, W1 + (size_t)e * HEXP * DMODEL,
                   DMODEL, HEXP, ((t >> 3) & 31) * 64, (t & 7) * 64, pool);
    } else if (bid < 16384) {       // wu -> W2
        const int e = (bid - 8192) >> 8, t = bid & 255;
        tconv_tile(wu + (size_t)e * DMODEL * HEXP, W2 + (size_t)e * HEXP * DMODEL,
                   DMODEL, HEXP, ((t >> 3) & 31) * 64, (t & 7) * 64, pool);
    } else if (bid < 16896) {       // sg [2048][1024] -> sgb [1024][2048]
        const int t = bid - 16384;
        tconv_tile(sg, sgb, DMODEL, HSH, (t >> 4) * 64, (t & 15) * 64, pool);
    } else if (bid < 17408) {       // su -> sub_
        const int t = bid - 16896;
        tconv_tile(su, sub_, DMODEL, HSH, (t >> 4) * 64, (t & 15) * 64, pool);
    } else {                        // xcast: x f32 -> xb bf16 (1024 elems/block)
        const int idx = bid - 17408;
        const int i = (idx * 256 + (int)threadIdx.x) * 4;
        const float4 v = *reinterpret_cast<const float4*>(x + i);
        ushort4 o;
        o.x = f2bf(v.x); o.y = f2bf(v.y); o.z = f2bf(v.z); o.w = f2bf(v.w);
        *reinterpret_cast<ushort4*>(xb + i) = o;
    }
}

// ---------------- grouping: pair lists + 128-row tile table + token->pos map ----
__global__ __launch_bounds__(1024)
void group_kernel(const int* __restrict__ inds, const float* __restrict__ scores,
                  int* __restrict__ meta, int* __restrict__ pair_token,
                  float* __restrict__ pair_score, int* __restrict__ tok_pos)
{
    __shared__ int cnt[NEXP];
    __shared__ int off_s[NEXP];
    __shared__ int cur[NEXP];
    const int tid = threadIdx.x;
    if (tid < NEXP) cnt[tid] = 0;
    __syncthreads();
    for (int i = tid; i < NPAIR; i += 1024) atomicAdd(&cnt[inds[i]], 1);
    __syncthreads();
    if (tid == 0) {
        int run = 0, nt1 = 0;
        for (int e = 0; e < NEXP; ++e) {
            off_s[e] = run;
            const int c = cnt[e];
            for (int m0 = 0; m0 < c; m0 += 128) {
                meta[M128_TE + nt1] = e;
                meta[M128_TP0 + nt1] = run + m0;
                meta[M128_TM + nt1] = (c - m0 < 128) ? (c - m0) : 128;
                ++nt1;
            }
            run += c;
        }
        meta[M128_NT] = nt1;
    }
    __syncthreads();
    if (tid < NEXP) cur[tid] = off_s[tid];
    __syncthreads();
    for (int i = tid; i < NPAIR; i += 1024) {
        const int e = inds[i];
        const int pos = atomicAdd(&cur[e], 1);
        pair_token[pos] = i >> 2;
        pair_score[pos] = scores[i];
        tok_pos[i] = pos;
    }
}

// ---------------- gate/up GEMM 128x128 + passenger tconv(wd -> wdb, sd -> sdb) ----
// grid 9728 (XCD-swizzled):
//   [0, 8*NT128)        expert tile (tt=bid>>3; r=bid&7: mat=r>>2, n0=(r&3)*128)
//   [8*NT128, +256)     shared tile
//   rest                passenger tconv (wd 8192 tiles, sd 512 tiles)
__global__ __launch_bounds__(256, 3)
void gu128_kernel(const unsigned short* __restrict__ xb,
                  const unsigned short* __restrict__ W1,
                  const unsigned short* __restrict__ W2,
                  const int* __restrict__ meta, const int* __restrict__ pair_token,
                  const unsigned short* __restrict__ sgb,
                  const unsigned short* __restrict__ sub_,
                  unsigned short* __restrict__ hexp, unsigned short* __restrict__ uexp,
                  unsigned short* __restrict__ shh, unsigned short* __restrict__ shu,
                  const float* __restrict__ wd, unsigned short* __restrict__ wdb,
                  const float* __restrict__ sd, unsigned short* __restrict__ sdb)
{
    constexpr int NT = DMODEL / 32;
    __shared__ unsigned short pool[16384];   // 32 KB (GEMM dbuf or tconv tile)
    auto Al = (unsigned short (*)[128][32])(pool);
    auto Bl = (unsigned short (*)[128][32])(pool + 8192);

    const int bid = swz8(blockIdx.x, 8 * NT128 + 256 + 8704);
    const int tid = threadIdx.x;
    const int lane = tid & 63;
    const int wave = tid >> 6;

    if (bid >= 8 * NT128 + 256) {   // ---- passenger tconv role ----
        const int idx = bid - (8 * NT128 + 256);
        if (idx < 8192) {           // wd [E][512][2048] -> wdb [E][2048][512]
            const int e = idx >> 8, t = idx & 255;
            tconv_tile(wd + (size_t)e * HEXP * DMODEL, wdb + (size_t)e * DMODEL * HEXP,
                       HEXP, DMODEL, (t >> 5) * 64, (t & 31) * 64, pool);
        } else {                    // sd [1024][2048] -> sdb [2048][1024]
            const int t = idx - 8192;
            tconv_tile(sd, sdb, HSH, DMODEL, (t >> 5) * 64, (t & 31) * 64, pool);
        }
        return;
    }

    const int fr = lane & 15, fq = lane >> 4;
    const int ko = frag_ko(fr, fq);
    const int sub = lane >> 2;
    const int col8 = src_col8(lane);
    const int wm = wave >> 1, wn = wave & 1;
    const f32x4 zero4 = {0.f, 0.f, 0.f, 0.f};

    const bool EXPERT = bid < 8 * NT128;
    int p0, mval, n0, NB;
    const unsigned short* B;
    unsigned short* obuf;
    int tok0, tok1;
    const int arow0 = wave * 32 + sub;
    if (EXPERT) {
        const int tt = bid >> 3;
        if (tt >= meta[M128_NT]) return;
        const int e = meta[M128_TE + tt];
        p0 = meta[M128_TP0 + tt];
        mval = meta[M128_TM + tt];
        const int r = bid & 7;
        const int mat = r >> 2;
        n0 = (r & 3) * 128;
        NB = HEXP;
        B = (mat ? W2 : W1) + (size_t)e * HEXP * DMODEL;
        obuf = mat ? uexp : hexp;
        int q0 = p0 + arow0;      if (q0 > NPAIR - 1) q0 = NPAIR - 1;
        int q1 = p0 + arow0 + 16; if (q1 > NPAIR - 1) q1 = NPAIR - 1;
        tok0 = pair_token[q0];
        tok1 = pair_token[q1];
    } else {
        const int idx = bid - 8 * NT128;   // 256 blocks: 16m x 8n x 2mats
        const int mat = idx & 1;
        n0 = ((idx >> 1) & 7) * 128;
        p0 = (idx >> 4) * 128;
        mval = 128;
        NB = HSH;
        B = mat ? sub_ : sgb;
        obuf = mat ? shu : shh;
        tok0 = p0 + arow0;
        tok1 = p0 + arow0 + 16;
    }

    const unsigned short* asrc0 = xb + (size_t)tok0 * DMODEL + col8;
    const unsigned short* asrc1 = xb + (size_t)tok1 * DMODEL + col8;
    const unsigned short* bsrc0 = B + (size_t)(n0 + arow0) * DMODEL + col8;
    const unsigned short* bsrc1 = B + (size_t)(n0 + arow0 + 16) * DMODEL + col8;

    auto stage = [&](int buf, int k0) {
        gload16(asrc0 + k0, &Al[buf][wave * 32][0]);
        gload16(asrc1 + k0, &Al[buf][wave * 32 + 16][0]);
        gload16(bsrc0 + k0, &Bl[buf][wave * 32][0]);
        gload16(bsrc1 + k0, &Bl[buf][wave * 32 + 16][0]);
    };

    f32x4 acc[4][4];
#pragma unroll
    for (int m = 0; m < 4; ++m)
#pragma unroll
        for (int n = 0; n < 4; ++n) acc[m][n] = zero4;

    auto compute = [&](int buf) {
        s16x8 af[4], bf[4];
#pragma unroll
        for (int m = 0; m < 4; ++m)
            af[m] = *reinterpret_cast<const s16x8*>(&Al[buf][wm * 64 + m * 16 + fr][ko]);
#pragma unroll
        for (int n = 0; n < 4; ++n)
            bf[n] = *reinterpret_cast<const s16x8*>(&Bl[buf][wn * 64 + n * 16 + fr][ko]);
#pragma unroll
        for (int m = 0; m < 4; ++m)
#pragma unroll
            for (int n = 0; n < 4; ++n)
                acc[m][n] = mfma16x16x32(af[m], bf[n], acc[m][n]);
    };

    stage(0, 0);
    __syncthreads();
#pragma unroll 1
    for (int t = 0; t < NT; ++t) {
        const int cur = t & 1;
        if (t + 1 < NT) stage(cur ^ 1, (t + 1) * 32);
        compute(cur);
        __syncthreads();
    }

#pragma unroll
    for (int m = 0; m < 4; ++m)
#pragma unroll
        for (int n = 0; n < 4; ++n) {
            const int col = n0 + wn * 64 + n * 16 + fr;
#pragma unroll
            for (int r = 0; r < 4; ++r) {
                const int rt = wm * 64 + m * 16 + fq * 4 + r;
                if (rt < mval)
                    obuf[(size_t)(p0 + rt) * NB + col] = f2bf(acc[m][n][r]);
            }
        }
}

// ---------------- swiglu combine: act = silu(h)*u (expert + shared) ----------------
__global__ __launch_bounds__(256)
void swiglu_kernel(const unsigned short* __restrict__ hexp,
                   const unsigned short* __restrict__ uexp,
                   unsigned short* __restrict__ act,
                   const unsigned short* __restrict__ shh,
                   const unsigned short* __restrict__ shu,
                   unsigned short* __restrict__ shact)
{
    constexpr size_t NE = (size_t)NPAIR * HEXP;   // 4194304
    const size_t i = ((size_t)blockIdx.x * 256 + threadIdx.x) * 8;
    const unsigned short *hp, *up;
    unsigned short* ap;
    size_t j;
    if (i < NE) { hp = hexp; up = uexp; ap = act; j = i; }
    else        { hp = shh;  up = shu;  ap = shact; j = i - NE; }
    const uint4 hv = *reinterpret_cast<const uint4*>(hp + j);
    const uint4 uv = *reinterpret_cast<const uint4*>(up + j);
    const unsigned short* hu = reinterpret_cast<const unsigned short*>(&hv);
    const unsigned short* uu = reinterpret_cast<const unsigned short*>(&uv);
    ushort4 o[2];
    unsigned short* ou = reinterpret_cast<unsigned short*>(o);
#pragma unroll
    for (int k = 0; k < 8; ++k) {
        const float h = bf2f(hu[k]);
        const float u = bf2f(uu[k]);
        ou[k] = f2bf(h / (1.f + __expf(-h)) * u);
    }
    *reinterpret_cast<uint4*>(ap + j) = *reinterpret_cast<const uint4*>(o);
}

// ---------------- down GEMM 128x128: expert(->ypair) + shared(->sdown) -------------
__global__ __launch_bounds__(256, 3)
void down128_kernel(const unsigned short* __restrict__ act,
                    const unsigned short* __restrict__ shact,
                    const unsigned short* __restrict__ wdb,
                    const unsigned short* __restrict__ sdb,
                    unsigned short* __restrict__ ypair,
                    float* __restrict__ sdown,
                    const int* __restrict__ meta,
                    const float* __restrict__ pair_score)
{
    __shared__ unsigned short Al[2][128][32];
    __shared__ unsigned short Bl[2][128][32];

    const int bid = swz8(blockIdx.x, 16 * NT128 + 256);
    const int tid = threadIdx.x;
    const int lane = tid & 63;
    const int wave = tid >> 6;
    const int fr = lane & 15, fq = lane >> 4;
    const int ko = frag_ko(fr, fq);
    const int sub = lane >> 2;
    const int col8 = src_col8(lane);
    const int wm = wave >> 1, wn = wave & 1;
    const f32x4 zero4 = {0.f, 0.f, 0.f, 0.f};

    const bool EXPERT = bid < 16 * NT128;
    int p0, mval, n0, KA;
    const unsigned short *Asrc, *B;
    if (EXPERT) {
        const int tt = bid >> 4;
        if (tt >= meta[M128_NT]) return;
        const int e = meta[M128_TE + tt];
        p0 = meta[M128_TP0 + tt];
        mval = meta[M128_TM + tt];
        n0 = (bid & 15) * 128;
        KA = HEXP;
        Asrc = act;
        B = wdb + (size_t)e * DMODEL * HEXP;
    } else {
        const int idx = bid - 16 * NT128;   // 256 blocks: 16m x 16n
        p0 = (idx >> 4) * 128;
        mval = 128;
        n0 = (idx & 15) * 128;
        KA = HSH;
        Asrc = shact;
        B = sdb;
    }
    const int NT = KA / 32;

    const int arow0 = wave * 32 + sub;
    const unsigned short* asrc0 = Asrc + (size_t)(p0 + arow0) * KA + col8;
    const unsigned short* asrc1 = Asrc + (size_t)(p0 + arow0 + 16) * KA + col8;
    const unsigned short* bsrc0 = B + (size_t)(n0 + arow0) * KA + col8;
    const unsigned short* bsrc1 = B + (size_t)(n0 + arow0 + 16) * KA + col8;

    auto stage = [&](int buf, int k0) {
        gload16(asrc0 + k0, &Al[buf][wave * 32][0]);
        gload16(asrc1 + k0, &Al[buf][wave * 32 + 16][0]);
        gload16(bsrc0 + k0, &Bl[buf][wave * 32][0]);
        gload16(bsrc1 + k0, &Bl[buf][wave * 32 + 16][0]);
    };

    f32x4 acc[4][4];
#pragma unroll
    for (int m = 0; m < 4; ++m)
#pragma unroll
        for (int n = 0; n < 4; ++n) acc[m][n] = zero4;

    auto compute = [&](int buf) {
        s16x8 af[4], bf[4];
#pragma unroll
        for (int m = 0; m < 4; ++m)
            af[m] = *reinterpret_cast<const s16x8*>(&Al[buf][wm * 64 + m * 16 + fr][ko]);
#pragma unroll
        for (int n = 0; n < 4; ++n)
            bf[n] = *reinterpret_cast<const s16x8*>(&Bl[buf][wn * 64 + n * 16 + fr][ko]);
#pragma unroll
        for (int m = 0; m < 4; ++m)
#pragma unroll
            for (int n = 0; n < 4; ++n)
                acc[m][n] = mfma16x16x32(af[m], bf[n], acc[m][n]);
    };

    stage(0, 0);
    __syncthreads();
#pragma unroll 1
    for (int t = 0; t < NT; ++t) {
        const int cur = t & 1;
        if (t + 1 < NT) stage(cur ^ 1, (t + 1) * 32);
        compute(cur);
        __syncthreads();
    }

#pragma unroll
    for (int m = 0; m < 4; ++m)
#pragma unroll
        for (int n = 0; n < 4; ++n) {
            const int col = n0 + wn * 64 + n * 16 + fr;
#pragma unroll
            for (int r = 0; r < 4; ++r) {
                const int rt = wm * 64 + m * 16 + fq * 4 + r;
                if (rt < mval) {
                    if (EXPERT) {
                        const int p = p0 + rt;
                        ypair[(size_t)p * DMODEL + col] = f2bf(acc[m][n][r] * pair_score[p]);
                    } else {
                        sdown[(size_t)(p0 + rt) * DMODEL + col] = acc[m][n][r];
                    }
                }
            }
        }
}

// ---------------- final: out = (sum_k ypair[pos_k])*c0 + sdown*c1 ----------------
__global__ __launch_bounds__(256)
void final_kernel(const unsigned short* __restrict__ ypair,
                  const float* __restrict__ sdown,
                  const float* __restrict__ coef, const int* __restrict__ tok_pos,
                  float* __restrict__ out)
{
    const int row = blockIdx.x;
    const int col = threadIdx.x * 8;
    float acc[8] = {0.f, 0.f, 0.f, 0.f, 0.f, 0.f, 0.f, 0.f};
#pragma unroll
    for (int k = 0; k < 4; ++k) {
        const int pos = tok_pos[row * 4 + k];
        const uint4 v = *reinterpret_cast<const uint4*>(ypair + (size_t)pos * DMODEL + col);
        const unsigned short* u = reinterpret_cast<const unsigned short*>(&v);
#pragma unroll
        for (int j = 0; j < 8; ++j) acc[j] += bf2f(u[j]);
    }
    const float c0 = coef[row * 2 + 0];
    const float c1 = coef[row * 2 + 1];
    const float* sd = sdown + (size_t)row * DMODEL + col;
    const float4 s0 = *reinterpret_cast<const float4*>(sd);
    const float4 s1 = *reinterpret_cast<const float4*>(sd + 4);
    float4 o0, o1;
    o0.x = acc[0] * c0 + s0.x * c1; o0.y = acc[1] * c0 + s0.y * c1;
    o0.z = acc[2] * c0 + s0.z * c1; o0.w = acc[3] * c0 + s0.w * c1;
    o1.x = acc[4] * c0 + s1.x * c1; o1.y = acc[5] * c0 + s1.y * c1;
    o1.z = acc[6] * c0 + s1.z * c1; o1.w = acc[7] * c0 + s1.w * c1;
    float* op = out + (size_t)row * DMODEL + col;
    *reinterpret_cast<float4*>(op) = o0;
    *reinterpret_cast<float4*>(op + 4) = o1;
}

// ---------------- launch ----------------
extern "C" void kernel_launch(void* const* d_in, const int* in_sizes, int n_in,
                              void* d_out, int out_size, void* d_ws, size_t ws_size,
                              hipStream_t stream)
{
    const float* x           = (const float*)d_in[0];
    const float* gate_w      = (const float*)d_in[1];
    const float* expert_bias = (const float*)d_in[2];
    const float* wg          = (const float*)d_in[3];
    const float* wu          = (const float*)d_in[4];
    const float* wd          = (const float*)d_in[5];
    const float* sg          = (const float*)d_in[6];
    const float* su          = (const float*)d_in[7];
    const float* sd          = (const float*)d_in[8];
    const float* coef_w      = (const float*)d_in[9];
    const float* coef_b      = (const float*)d_in[10];
    float* out = (float*)d_out;

    char* ws = (char*)d_ws;
    size_t off = 0;
    auto take = [&](size_t bytes) {
        char* p = ws + off;
        off = (off + bytes + 255) & ~(size_t)255;
        return p;
    };
    int*   inds     = (int*)  take((size_t)S_TOK * 4 * sizeof(int));
    float* scores   = (float*)take((size_t)S_TOK * 4 * sizeof(float));
    float* coefp    = (float*)take((size_t)S_TOK * 2 * sizeof(float));
    int*   meta     = (int*)  take((size_t)META_SIZE * sizeof(int));
    int*   pair_tok = (int*)  take((size_t)NPAIR * sizeof(int));
    float* pair_sc  = (float*)take((size_t)NPAIR * sizeof(float));
    int*   tok_pos  = (int*)  take((size_t)NPAIR * sizeof(int));
    unsigned short* xb    = (unsigned short*)take((size_t)S_TOK * DMODEL * 2);
    unsigned short* act   = (unsigned short*)take((size_t)NPAIR * HEXP * 2);
    unsigned short* hexp  = (unsigned short*)take((size_t)NPAIR * HEXP * 2);
    unsigned short* uexp  = (unsigned short*)take((size_t)NPAIR * HEXP * 2);
    unsigned short* shact = (unsigned short*)take((size_t)S_TOK * HSH * 2);
    unsigned short* shh   = (unsigned short*)take((size_t)S_TOK * HSH * 2);
    unsigned short* shu   = (unsigned short*)take((size_t)S_TOK * HSH * 2);
    unsigned short* ypair = (unsigned short*)take((size_t)NPAIR * DMODEL * 2);  // 33.5MB
    float*          sdown = (float*)take((size_t)S_TOK * DMODEL * 4);           // 16.8MB
    unsigned short* sgb   = (unsigned short*)take((size_t)HSH * DMODEL * 2);
    unsigned short* sub_  = (unsigned short*)take((size_t)HSH * DMODEL * 2);
    unsigned short* sdb   = (unsigned short*)take((size_t)DMODEL * HSH * 2);
    unsigned short* W1    = (unsigned short*)take((size_t)NEXP * DMODEL * HEXP * 2); // 67MB
    unsigned short* W2    = (unsigned short*)take((size_t)NEXP * DMODEL * HEXP * 2); // 67MB
    unsigned short* wdb   = (unsigned short*)take((size_t)NEXP * DMODEL * HEXP * 2); // 67MB
    (void)ws_size; (void)in_sizes; (void)n_in; (void)out_size;

    router_kernel<<<S_TOK, 256, 0, stream>>>(x, gate_w, expert_bias, coef_w, coef_b,
                                             inds, scores, coefp);
    group_kernel<<<1, 1024, 0, stream>>>(inds, scores, meta, pair_tok, pair_sc, tok_pos);

    // wg/wu/sg/su conversions + xcast passengers (XCD-swizzled single dispatch)
    tconv_all_kernel<<<21504, 256, 0, stream>>>(wg, wu, sg, su, W1, W2, sgb, sub_, x, xb);

    // gate/up GEMMs (768 expert + 256 shared) + 8704 passenger tconv blocks
    gu128_kernel<<<8 * NT128 + 256 + 8704, 256, 0, stream>>>(
        xb, W1, W2, meta, pair_tok, sgb, sub_, hexp, uexp, shh, shu,
        wd, wdb, sd, sdb);

    // act = silu(h)*u for expert and shared (6.29M elems, 8/thread)
    swiglu_kernel<<<3072, 256, 0, stream>>>(hexp, uexp, act, shh, shu, shact);

    // down GEMMs: expert (1536 -> ypair) + shared (256 -> sdown)
    down128_kernel<<<16 * NT128 + 256, 256, 0, stream>>>(
        act, shact, wdb, sdb, ypair, sdown, meta, pair_sc);

    // final combine (each out element written exactly once)
    final_kernel<<<S_TOK, 256, 0, stream>>>(ypair, sdown, coefp, tok_pos, out);
}

// Round 17
// 329.593 us; speedup vs baseline: 2.4890x; 2.4890x over previous
//
#include <hip/hip_runtime.h>
#include <hip/hip_bf16.h>
#include <stdint.h>

// ---------------- problem dims (fixed by setup_inputs) ----------------
#define S_TOK   2048   // tokens (B*S)
#define DMODEL  2048   // D
#define HEXP    512    // H per expert
#define NEXP    32     // E
#define HSH     1024   // shared hidden
#define NPAIR   (S_TOK * 4)   // 8192 (token,expert) pairs, top_k=4
#define NT128   96            // sum ceil(cnt_e/128) <= 8192/128 + 32

// meta layout (ints): 128-row tile table
#define M128_NT  0
#define M128_TE  1
#define M128_TP0 (1 + NT128)
#define M128_TM  (1 + 2 * NT128)
#define META_SIZE (1 + 3 * NT128)

typedef short  s16x8 __attribute__((ext_vector_type(8)));
typedef __bf16 b16x8 __attribute__((ext_vector_type(8)));
typedef float  f32x4 __attribute__((ext_vector_type(4)));

__device__ __forceinline__ f32x4 mfma16x16x32(s16x8 a, s16x8 b, f32x4 c) {
    return __builtin_amdgcn_mfma_f32_16x16x32_bf16(
        __builtin_bit_cast(b16x8, a), __builtin_bit_cast(b16x8, b), c, 0, 0, 0);
}

__device__ __forceinline__ unsigned short f2bf(float f) {
    union { float f; unsigned int u; } v; v.f = f;
    unsigned int u = v.u;
    return (unsigned short)((u + 0x7FFFu + ((u >> 16) & 1u)) >> 16);  // RNE
}

__device__ __forceinline__ float bf2f(unsigned short b) {
    union { unsigned int u; float f; } v; v.u = ((unsigned int)b) << 16;
    return v.f;
}

// async global->LDS, 16B per lane. LDS dest is wave-uniform base + lane*16.
__device__ __forceinline__ void gload16(const unsigned short* g, unsigned short* l) {
    __builtin_amdgcn_global_load_lds(
        (const __attribute__((address_space(1))) void*)(uintptr_t)g,
        (__attribute__((address_space(3))) void*)(uintptr_t)l, 16, 0, 0);
}

// ---- LDS bank swizzle for [row][32-short] GEMM tiles (64B rows) ----
__device__ __forceinline__ int src_col8(int lane) {
    return 8 * ((lane & 3) ^ ((lane >> 3) & 3));
}
__device__ __forceinline__ int frag_ko(int fr, int fq) {
    return 8 * (fq ^ ((fr >> 1) & 3));
}

// ---------------- transpose-convert tile: f32 [K][N] -> bf16 [N][K] ----------------
// LDS [64][64] with XOR-swizzled columns: T[n][k ^ key(n)], key(n)=((n>>2)&7)<<3.
// Fill: 16 columnar writers spread over 8 banks (2-way, free). Drain: two 16B-aligned
// uint4 reads at kc^key and (kc+8)^key; global writes 2x16B contiguous.
// [validated r16: gu128 passenger conflicts 3.34M -> 1.11M, correctness passed]
__device__ __forceinline__ void tconv_tile(const float* __restrict__ s,
                                           unsigned short* __restrict__ d,
                                           const int K, const int N,
                                           const int k0, const int n0,
                                           unsigned short* pool)   // >= 4096 shorts
{
    auto T = (unsigned short (*)[64])pool;
    const int tid = threadIdx.x;
    const int n4 = (tid & 15) * 4;
    const int kr = tid >> 4;
    const int wkey = ((n4 >> 2) & 7) << 3;   // shared by rows n4..n4+3
#pragma unroll
    for (int i = 0; i < 4; ++i) {
        const int k = kr + i * 16;
        const float4 v = *reinterpret_cast<const float4*>(s + (size_t)(k0 + k) * N + n0 + n4);
        const int kk = k ^ wkey;
        T[n4 + 0][kk] = f2bf(v.x);
        T[n4 + 1][kk] = f2bf(v.y);
        T[n4 + 2][kk] = f2bf(v.z);
        T[n4 + 3][kk] = f2bf(v.w);
    }
    __syncthreads();
    const int nw = tid >> 2;
    const int kc = (tid & 3) * 16;
    const int rkey = ((nw >> 2) & 7) << 3;
    const uint4 w0 = *reinterpret_cast<const uint4*>(&T[nw][kc ^ rkey]);
    const uint4 w1 = *reinterpret_cast<const uint4*>(&T[nw][(kc + 8) ^ rkey]);
    unsigned short* o = d + (size_t)(n0 + nw) * K + k0 + kc;   // 16B-aligned
    *reinterpret_cast<uint4*>(o)     = w0;
    *reinterpret_cast<uint4*>(o + 8) = w1;
}

// ---------------- router: logits, sigmoid, biased top-4, coef softmax ----------------
__global__ __launch_bounds__(256)
void router_kernel(const float* __restrict__ x, const float* __restrict__ gate_w,
                   const float* __restrict__ expert_bias,
                   const float* __restrict__ coef_w, const float* __restrict__ coef_b,
                   int* __restrict__ inds, float* __restrict__ scores,
                   float* __restrict__ coefo)
{
    const int t = blockIdx.x;
    const int tid = threadIdx.x;
    const int lane = tid & 63;
    const int wave = tid >> 6;
    const float* xr = x + (size_t)t * DMODEL;

    float xv[32];
#pragma unroll
    for (int j = 0; j < 32; ++j) xv[j] = xr[lane + 64 * j];

    __shared__ float s_logits[NEXP];
    __shared__ float s_coef[2];

    for (int i = 0; i < 8; ++i) {
        const int e = wave * 8 + i;
        const float* wr = gate_w + (size_t)e * DMODEL;
        float p = 0.f;
#pragma unroll
        for (int j = 0; j < 32; ++j) p += xv[j] * wr[lane + 64 * j];
#pragma unroll
        for (int o = 32; o > 0; o >>= 1) p += __shfl_xor(p, o);
        if (lane == 0) s_logits[e] = p;
    }
    if (wave == 0) {
        for (int c = 0; c < 2; ++c) {
            const float* wr = coef_w + (size_t)c * DMODEL;
            float p = 0.f;
#pragma unroll
            for (int j = 0; j < 32; ++j) p += xv[j] * wr[lane + 64 * j];
#pragma unroll
            for (int o = 32; o > 0; o >>= 1) p += __shfl_xor(p, o);
            if (lane == 0) s_coef[c] = p;
        }
    }
    __syncthreads();
    if (tid == 0) {
        float routing[NEXP], biased[NEXP];
        for (int e = 0; e < NEXP; ++e) {
            const float r = 1.f / (1.f + expf(-s_logits[e]));
            routing[e] = r;
            biased[e] = r + expert_bias[e];
        }
        int sel[4]; float sc[4]; float ssum = 0.f;
        for (int k = 0; k < 4; ++k) {
            int best = 0; float bv = -1e30f;
            for (int e = 0; e < NEXP; ++e)
                if (biased[e] > bv) { bv = biased[e]; best = e; }  // strict > = lax.top_k tie rule
            sel[k] = best; sc[k] = routing[best]; ssum += sc[k];
            biased[best] = -1e30f;
        }
        const float inv = 1.f / (ssum + 1e-20f);
        for (int k = 0; k < 4; ++k) {
            inds[t * 4 + k] = sel[k];
            scores[t * 4 + k] = sc[k] * inv;
        }
        const float l0 = s_coef[0] + coef_b[0];
        const float l1 = s_coef[1] + coef_b[1];
        const float m = fmaxf(l0, l1);
        const float e0 = expf(l0 - m), e1 = expf(l1 - m);
        coefo[t * 2 + 0] = e0 / (e0 + e1);
        coefo[t * 2 + 1] = e1 / (e0 + e1);
    }
}

// ---------------- upfront tconv: wg, wu, sg, su + xcast passengers -----------------
// grid 21504 (NO cross-role swizzle -- r16 lesson): wg 8192 | wu 8192 | sg 512 |
// su 512 | xcast 4096
__global__ __launch_bounds__(256)
void tconv_all_kernel(const float* __restrict__ wg, const float* __restrict__ wu,
                      const float* __restrict__ sg, const float* __restrict__ su,
                      unsigned short* __restrict__ W1, unsigned short* __restrict__ W2,
                      unsigned short* __restrict__ sgb, unsigned short* __restrict__ sub_,
                      const float* __restrict__ x, unsigned short* __restrict__ xb)
{
    __shared__ unsigned short pool[64 * 64];
    const int bid = blockIdx.x;
    if (bid < 8192) {               // wg [E][2048][512] -> W1 [E][512][2048]
        const int e = bid >> 8, t = bid & 255;
        tconv_tile(wg + (size_t)e * DMODEL * HEXP, W1 + (size_t)e * HEXP * DMODEL,
                   DMODEL, HEXP, ((t >> 3) & 31) * 64, (t & 7) * 64, pool);
    } else if (bid < 16384) {       // wu -> W2
        const int e = (bid - 8192) >> 8, t = bid & 255;
        tconv_tile(wu + (size_t)e * DMODEL * HEXP, W2 + (size_t)e * HEXP * DMODEL,
                   DMODEL, HEXP, ((t >> 3) & 31) * 64, (t & 7) * 64, pool);
    } else if (bid < 16896) {       // sg [2048][1024] -> sgb [1024][2048]
        const int t = bid - 16384;
        tconv_tile(sg, sgb, DMODEL, HSH, (t >> 4) * 64, (t & 15) * 64, pool);
    } else if (bid < 17408) {       // su -> sub_
        const int t = bid - 16896;
        tconv_tile(su, sub_, DMODEL, HSH, (t >> 4) * 64, (t & 15) * 64, pool);
    } else {                        // xcast: x f32 -> xb bf16 (1024 elems/block)
        const int idx = bid - 17408;
        const int i = (idx * 256 + (int)threadIdx.x) * 4;
        const float4 v = *reinterpret_cast<const float4*>(x + i);
        ushort4 o;
        o.x = f2bf(v.x); o.y = f2bf(v.y); o.z = f2bf(v.z); o.w = f2bf(v.w);
        *reinterpret_cast<ushort4*>(xb + i) = o;
    }
}

// ---------------- grouping: pair lists + 128-row tile table + token->pos map ----
__global__ __launch_bounds__(1024)
void group_kernel(const int* __restrict__ inds, const float* __restrict__ scores,
                  int* __restrict__ meta, int* __restrict__ pair_token,
                  float* __restrict__ pair_score, int* __restrict__ tok_pos)
{
    __shared__ int cnt[NEXP];
    __shared__ int off_s[NEXP];
    __shared__ int cur[NEXP];
    const int tid = threadIdx.x;
    if (tid < NEXP) cnt[tid] = 0;
    __syncthreads();
    for (int i = tid; i < NPAIR; i += 1024) atomicAdd(&cnt[inds[i]], 1);
    __syncthreads();
    if (tid == 0) {
        int run = 0, nt1 = 0;
        for (int e = 0; e < NEXP; ++e) {
            off_s[e] = run;
            const int c = cnt[e];
            for (int m0 = 0; m0 < c; m0 += 128) {
                meta[M128_TE + nt1] = e;
                meta[M128_TP0 + nt1] = run + m0;
                meta[M128_TM + nt1] = (c - m0 < 128) ? (c - m0) : 128;
                ++nt1;
            }
            run += c;
        }
        meta[M128_NT] = nt1;
    }
    __syncthreads();
    if (tid < NEXP) cur[tid] = off_s[tid];
    __syncthreads();
    for (int i = tid; i < NPAIR; i += 1024) {
        const int e = inds[i];
        const int pos = atomicAdd(&cur[e], 1);
        pair_token[pos] = i >> 2;
        pair_score[pos] = scores[i];
        tok_pos[i] = pos;
    }
}

// ---------------- gate/up GEMM 128x128 + passenger tconv(wd -> wdb, sd -> sdb) ----
// grid 9728 (NO cross-role swizzle):
//   [0, 8*NT128)        expert tile (tt=bid>>3; r=bid&7: mat=r>>2, n0=(r&3)*128)
//   [8*NT128, +256)     shared tile
//   rest                passenger tconv (wd 8192 tiles, sd 512 tiles)
__global__ __launch_bounds__(256, 3)
void gu128_kernel(const unsigned short* __restrict__ xb,
                  const unsigned short* __restrict__ W1,
                  const unsigned short* __restrict__ W2,
                  const int* __restrict__ meta, const int* __restrict__ pair_token,
                  const unsigned short* __restrict__ sgb,
                  const unsigned short* __restrict__ sub_,
                  unsigned short* __restrict__ hexp, unsigned short* __restrict__ uexp,
                  unsigned short* __restrict__ shh, unsigned short* __restrict__ shu,
                  const float* __restrict__ wd, unsigned short* __restrict__ wdb,
                  const float* __restrict__ sd, unsigned short* __restrict__ sdb)
{
    constexpr int NT = DMODEL / 32;
    __shared__ unsigned short pool[16384];   // 32 KB (GEMM dbuf or tconv tile)
    auto Al = (unsigned short (*)[128][32])(pool);
    auto Bl = (unsigned short (*)[128][32])(pool + 8192);

    const int bid = blockIdx.x;
    const int tid = threadIdx.x;
    const int lane = tid & 63;
    const int wave = tid >> 6;

    if (bid >= 8 * NT128 + 256) {   // ---- passenger tconv role ----
        const int idx = bid - (8 * NT128 + 256);
        if (idx < 8192) {           // wd [E][512][2048] -> wdb [E][2048][512]
            const int e = idx >> 8, t = idx & 255;
            tconv_tile(wd + (size_t)e * HEXP * DMODEL, wdb + (size_t)e * DMODEL * HEXP,
                       HEXP, DMODEL, (t >> 5) * 64, (t & 31) * 64, pool);
        } else {                    // sd [1024][2048] -> sdb [2048][1024]
            const int t = idx - 8192;
            tconv_tile(sd, sdb, HSH, DMODEL, (t >> 5) * 64, (t & 31) * 64, pool);
        }
        return;
    }

    const int fr = lane & 15, fq = lane >> 4;
    const int ko = frag_ko(fr, fq);
    const int sub = lane >> 2;
    const int col8 = src_col8(lane);
    const int wm = wave >> 1, wn = wave & 1;
    const f32x4 zero4 = {0.f, 0.f, 0.f, 0.f};

    const bool EXPERT = bid < 8 * NT128;
    int p0, mval, n0, NB;
    const unsigned short* B;
    unsigned short* obuf;
    int tok0, tok1;
    const int arow0 = wave * 32 + sub;
    if (EXPERT) {
        const int tt = bid >> 3;
        if (tt >= meta[M128_NT]) return;
        const int e = meta[M128_TE + tt];
        p0 = meta[M128_TP0 + tt];
        mval = meta[M128_TM + tt];
        const int r = bid & 7;
        const int mat = r >> 2;
        n0 = (r & 3) * 128;
        NB = HEXP;
        B = (mat ? W2 : W1) + (size_t)e * HEXP * DMODEL;
        obuf = mat ? uexp : hexp;
        int q0 = p0 + arow0;      if (q0 > NPAIR - 1) q0 = NPAIR - 1;
        int q1 = p0 + arow0 + 16; if (q1 > NPAIR - 1) q1 = NPAIR - 1;
        tok0 = pair_token[q0];
        tok1 = pair_token[q1];
    } else {
        const int idx = bid - 8 * NT128;   // 256 blocks: 16m x 8n x 2mats
        const int mat = idx & 1;
        n0 = ((idx >> 1) & 7) * 128;
        p0 = (idx >> 4) * 128;
        mval = 128;
        NB = HSH;
        B = mat ? sub_ : sgb;
        obuf = mat ? shu : shh;
        tok0 = p0 + arow0;
        tok1 = p0 + arow0 + 16;
    }

    const unsigned short* asrc0 = xb + (size_t)tok0 * DMODEL + col8;
    const unsigned short* asrc1 = xb + (size_t)tok1 * DMODEL + col8;
    const unsigned short* bsrc0 = B + (size_t)(n0 + arow0) * DMODEL + col8;
    const unsigned short* bsrc1 = B + (size_t)(n0 + arow0 + 16) * DMODEL + col8;

    auto stage = [&](int buf, int k0) {
        gload16(asrc0 + k0, &Al[buf][wave * 32][0]);
        gload16(asrc1 + k0, &Al[buf][wave * 32 + 16][0]);
        gload16(bsrc0 + k0, &Bl[buf][wave * 32][0]);
        gload16(bsrc1 + k0, &Bl[buf][wave * 32 + 16][0]);
    };

    f32x4 acc[4][4];
#pragma unroll
    for (int m = 0; m < 4; ++m)
#pragma unroll
        for (int n = 0; n < 4; ++n) acc[m][n] = zero4;

    auto compute = [&](int buf) {
        s16x8 af[4], bf[4];
#pragma unroll
        for (int m = 0; m < 4; ++m)
            af[m] = *reinterpret_cast<const s16x8*>(&Al[buf][wm * 64 + m * 16 + fr][ko]);
#pragma unroll
        for (int n = 0; n < 4; ++n)
            bf[n] = *reinterpret_cast<const s16x8*>(&Bl[buf][wn * 64 + n * 16 + fr][ko]);
#pragma unroll
        for (int m = 0; m < 4; ++m)
#pragma unroll
            for (int n = 0; n < 4; ++n)
                acc[m][n] = mfma16x16x32(af[m], bf[n], acc[m][n]);
    };

    stage(0, 0);
    __syncthreads();
#pragma unroll 1
    for (int t = 0; t < NT; ++t) {
        const int cur = t & 1;
        if (t + 1 < NT) stage(cur ^ 1, (t + 1) * 32);
        compute(cur);
        __syncthreads();
    }

#pragma unroll
    for (int m = 0; m < 4; ++m)
#pragma unroll
        for (int n = 0; n < 4; ++n) {
            const int col = n0 + wn * 64 + n * 16 + fr;
#pragma unroll
            for (int r = 0; r < 4; ++r) {
                const int rt = wm * 64 + m * 16 + fq * 4 + r;
                if (rt < mval)
                    obuf[(size_t)(p0 + rt) * NB + col] = f2bf(acc[m][n][r]);
            }
        }
}

// ---------------- swiglu combine: act = silu(h)*u (expert + shared) ----------------
__global__ __launch_bounds__(256)
void swiglu_kernel(const unsigned short* __restrict__ hexp,
                   const unsigned short* __restrict__ uexp,
                   unsigned short* __restrict__ act,
                   const unsigned short* __restrict__ shh,
                   const unsigned short* __restrict__ shu,
                   unsigned short* __restrict__ shact)
{
    constexpr size_t NE = (size_t)NPAIR * HEXP;   // 4194304
    const size_t i = ((size_t)blockIdx.x * 256 + threadIdx.x) * 8;
    const unsigned short *hp, *up;
    unsigned short* ap;
    size_t j;
    if (i < NE) { hp = hexp; up = uexp; ap = act; j = i; }
    else        { hp = shh;  up = shu;  ap = shact; j = i - NE; }
    const uint4 hv = *reinterpret_cast<const uint4*>(hp + j);
    const uint4 uv = *reinterpret_cast<const uint4*>(up + j);
    const unsigned short* hu = reinterpret_cast<const unsigned short*>(&hv);
    const unsigned short* uu = reinterpret_cast<const unsigned short*>(&uv);
    ushort4 o[2];
    unsigned short* ou = reinterpret_cast<unsigned short*>(o);
#pragma unroll
    for (int k = 0; k < 8; ++k) {
        const float h = bf2f(hu[k]);
        const float u = bf2f(uu[k]);
        ou[k] = f2bf(h / (1.f + __expf(-h)) * u);
    }
    *reinterpret_cast<uint4*>(ap + j) = *reinterpret_cast<const uint4*>(o);
}

// ---------------- down GEMM 128x128: expert(->ypair) + shared(->sdown) -------------
__global__ __launch_bounds__(256, 3)
void down128_kernel(const unsigned short* __restrict__ act,
                    const unsigned short* __restrict__ shact,
                    const unsigned short* __restrict__ wdb,
                    const unsigned short* __restrict__ sdb,
                    unsigned short* __restrict__ ypair,
                    float* __restrict__ sdown,
                    const int* __restrict__ meta,
                    const float* __restrict__ pair_score)
{
    __shared__ unsigned short Al[2][128][32];
    __shared__ unsigned short Bl[2][128][32];

    const int bid = blockIdx.x;
    const int tid = threadIdx.x;
    const int lane = tid & 63;
    const int wave = tid >> 6;
    const int fr = lane & 15, fq = lane >> 4;
    const int ko = frag_ko(fr, fq);
    const int sub = lane >> 2;
    const int col8 = src_col8(lane);
    const int wm = wave >> 1, wn = wave & 1;
    const f32x4 zero4 = {0.f, 0.f, 0.f, 0.f};

    const bool EXPERT = bid < 16 * NT128;
    int p0, mval, n0, KA;
    const unsigned short *Asrc, *B;
    if (EXPERT) {
        const int tt = bid >> 4;
        if (tt >= meta[M128_NT]) return;
        const int e = meta[M128_TE + tt];
        p0 = meta[M128_TP0 + tt];
        mval = meta[M128_TM + tt];
        n0 = (bid & 15) * 128;
        KA = HEXP;
        Asrc = act;
        B = wdb + (size_t)e * DMODEL * HEXP;
    } else {
        const int idx = bid - 16 * NT128;   // 256 blocks: 16m x 16n
        p0 = (idx >> 4) * 128;
        mval = 128;
        n0 = (idx & 15) * 128;
        KA = HSH;
        Asrc = shact;
        B = sdb;
    }
    const int NT = KA / 32;

    const int arow0 = wave * 32 + sub;
    const unsigned short* asrc0 = Asrc + (size_t)(p0 + arow0) * KA + col8;
    const unsigned short* asrc1 = Asrc + (size_t)(p0 + arow0 + 16) * KA + col8;
    const unsigned short* bsrc0 = B + (size_t)(n0 + arow0) * KA + col8;
    const unsigned short* bsrc1 = B + (size_t)(n0 + arow0 + 16) * KA + col8;

    auto stage = [&](int buf, int k0) {
        gload16(asrc0 + k0, &Al[buf][wave * 32][0]);
        gload16(asrc1 + k0, &Al[buf][wave * 32 + 16][0]);
        gload16(bsrc0 + k0, &Bl[buf][wave * 32][0]);
        gload16(bsrc1 + k0, &Bl[buf][wave * 32 + 16][0]);
    };

    f32x4 acc[4][4];
#pragma unroll
    for (int m = 0; m < 4; ++m)
#pragma unroll
        for (int n = 0; n < 4; ++n) acc[m][n] = zero4;

    auto compute = [&](int buf) {
        s16x8 af[4], bf[4];
#pragma unroll
        for (int m = 0; m < 4; ++m)
            af[m] = *reinterpret_cast<const s16x8*>(&Al[buf][wm * 64 + m * 16 + fr][ko]);
#pragma unroll
        for (int n = 0; n < 4; ++n)
            bf[n] = *reinterpret_cast<const s16x8*>(&Bl[buf][wn * 64 + n * 16 + fr][ko]);
#pragma unroll
        for (int m = 0; m < 4; ++m)
#pragma unroll
            for (int n = 0; n < 4; ++n)
                acc[m][n] = mfma16x16x32(af[m], bf[n], acc[m][n]);
    };

    stage(0, 0);
    __syncthreads();
#pragma unroll 1
    for (int t = 0; t < NT; ++t) {
        const int cur = t & 1;
        if (t + 1 < NT) stage(cur ^ 1, (t + 1) * 32);
        compute(cur);
        __syncthreads();
    }

#pragma unroll
    for (int m = 0; m < 4; ++m)
#pragma unroll
        for (int n = 0; n < 4; ++n) {
            const int col = n0 + wn * 64 + n * 16 + fr;
#pragma unroll
            for (int r = 0; r < 4; ++r) {
                const int rt = wm * 64 + m * 16 + fq * 4 + r;
                if (rt < mval) {
                    if (EXPERT) {
                        const int p = p0 + rt;
                        ypair[(size_t)p * DMODEL + col] = f2bf(acc[m][n][r] * pair_score[p]);
                    } else {
                        sdown[(size_t)(p0 + rt) * DMODEL + col] = acc[m][n][r];
                    }
                }
            }
        }
}

// ---------------- final: out = (sum_k ypair[pos_k])*c0 + sdown*c1 ----------------
__global__ __launch_bounds__(256)
void final_kernel(const unsigned short* __restrict__ ypair,
                  const float* __restrict__ sdown,
                  const float* __restrict__ coef, const int* __restrict__ tok_pos,
                  float* __restrict__ out)
{
    const int row = blockIdx.x;
    const int col = threadIdx.x * 8;
    float acc[8] = {0.f, 0.f, 0.f, 0.f, 0.f, 0.f, 0.f, 0.f};
#pragma unroll
    for (int k = 0; k < 4; ++k) {
        const int pos = tok_pos[row * 4 + k];
        const uint4 v = *reinterpret_cast<const uint4*>(ypair + (size_t)pos * DMODEL + col);
        const unsigned short* u = reinterpret_cast<const unsigned short*>(&v);
#pragma unroll
        for (int j = 0; j < 8; ++j) acc[j] += bf2f(u[j]);
    }
    const float c0 = coef[row * 2 + 0];
    const float c1 = coef[row * 2 + 1];
    const float* sd = sdown + (size_t)row * DMODEL + col;
    const float4 s0 = *reinterpret_cast<const float4*>(sd);
    const float4 s1 = *reinterpret_cast<const float4*>(sd + 4);
    float4 o0, o1;
    o0.x = acc[0] * c0 + s0.x * c1; o0.y = acc[1] * c0 + s0.y * c1;
    o0.z = acc[2] * c0 + s0.z * c1; o0.w = acc[3] * c0 + s0.w * c1;
    o1.x = acc[4] * c0 + s1.x * c1; o1.y = acc[5] * c0 + s1.y * c1;
    o1.z = acc[6] * c0 + s1.z * c1; o1.w = acc[7] * c0 + s1.w * c1;
    float* op = out + (size_t)row * DMODEL + col;
    *reinterpret_cast<float4*>(op) = o0;
    *reinterpret_cast<float4*>(op + 4) = o1;
}

// ---------------- launch ----------------
extern "C" void kernel_launch(void* const* d_in, const int* in_sizes, int n_in,
                              void* d_out, int out_size, void* d_ws, size_t ws_size,
                              hipStream_t stream)
{
    const float* x           = (const float*)d_in[0];
    const float* gate_w      = (const float*)d_in[1];
    const float* expert_bias = (const float*)d_in[2];
    const float* wg          = (const float*)d_in[3];
    const float* wu          = (const float*)d_in[4];
    const float* wd          = (const float*)d_in[5];
    const float* sg          = (const float*)d_in[6];
    const float* su          = (const float*)d_in[7];
    const float* sd          = (const float*)d_in[8];
    const float* coef_w      = (const float*)d_in[9];
    const float* coef_b      = (const float*)d_in[10];
    float* out = (float*)d_out;

    char* ws = (char*)d_ws;
    size_t off = 0;
    auto take = [&](size_t bytes) {
        char* p = ws + off;
        off = (off + bytes + 255) & ~(size_t)255;
        return p;
    };
    int*   inds     = (int*)  take((size_t)S_TOK * 4 * sizeof(int));
    float* scores   = (float*)take((size_t)S_TOK * 4 * sizeof(float));
    float* coefp    = (float*)take((size_t)S_TOK * 2 * sizeof(float));
    int*   meta     = (int*)  take((size_t)META_SIZE * sizeof(int));
    int*   pair_tok = (int*)  take((size_t)NPAIR * sizeof(int));
    float* pair_sc  = (float*)take((size_t)NPAIR * sizeof(float));
    int*   tok_pos  = (int*)  take((size_t)NPAIR * sizeof(int));
    unsigned short* xb    = (unsigned short*)take((size_t)S_TOK * DMODEL * 2);
    unsigned short* act   = (unsigned short*)take((size_t)NPAIR * HEXP * 2);
    unsigned short* hexp  = (unsigned short*)take((size_t)NPAIR * HEXP * 2);
    unsigned short* uexp  = (unsigned short*)take((size_t)NPAIR * HEXP * 2);
    unsigned short* shact = (unsigned short*)take((size_t)S_TOK * HSH * 2);
    unsigned short* shh   = (unsigned short*)take((size_t)S_TOK * HSH * 2);
    unsigned short* shu   = (unsigned short*)take((size_t)S_TOK * HSH * 2);
    unsigned short* ypair = (unsigned short*)take((size_t)NPAIR * DMODEL * 2);  // 33.5MB
    float*          sdown = (float*)take((size_t)S_TOK * DMODEL * 4);           // 16.8MB
    unsigned short* sgb   = (unsigned short*)take((size_t)HSH * DMODEL * 2);
    unsigned short* sub_  = (unsigned short*)take((size_t)HSH * DMODEL * 2);
    unsigned short* sdb   = (unsigned short*)take((size_t)DMODEL * HSH * 2);
    unsigned short* W1    = (unsigned short*)take((size_t)NEXP * DMODEL * HEXP * 2); // 67MB
    unsigned short* W2    = (unsigned short*)take((size_t)NEXP * DMODEL * HEXP * 2); // 67MB
    unsigned short* wdb   = (unsigned short*)take((size_t)NEXP * DMODEL * HEXP * 2); // 67MB
    (void)ws_size; (void)in_sizes; (void)n_in; (void)out_size;

    router_kernel<<<S_TOK, 256, 0, stream>>>(x, gate_w, expert_bias, coef_w, coef_b,
                                             inds, scores, coefp);
    group_kernel<<<1, 1024, 0, stream>>>(inds, scores, meta, pair_tok, pair_sc, tok_pos);

    // wg/wu/sg/su conversions + xcast passengers (single dispatch)
    tconv_all_kernel<<<21504, 256, 0, stream>>>(wg, wu, sg, su, W1, W2, sgb, sub_, x, xb);

    // gate/up GEMMs (768 expert + 256 shared) + 8704 passenger tconv blocks
    gu128_kernel<<<8 * NT128 + 256 + 8704, 256, 0, stream>>>(
        xb, W1, W2, meta, pair_tok, sgb, sub_, hexp, uexp, shh, shu,
        wd, wdb, sd, sdb);

    // act = silu(h)*u for expert and shared (6.29M elems, 8/thread)
    swiglu_kernel<<<3072, 256, 0, stream>>>(hexp, uexp, act, shh, shu, shact);

    // down GEMMs: expert (1536 -> ypair) + shared (256 -> sdown)
    down128_kernel<<<16 * NT128 + 256, 256, 0, stream>>>(
        act, shact, wdb, sdb, ypair, sdown, meta, pair_sc);

    // final combine (each out element written exactly once)
    final_kernel<<<S_TOK, 256, 0, stream>>>(ypair, sdown, coefp, tok_pos, out);
}

// Round 18
// 323.701 us; speedup vs baseline: 2.5343x; 1.0182x over previous
//
#include <hip/hip_runtime.h>
#include <hip/hip_bf16.h>
#include <stdint.h>

// ---------------- problem dims (fixed by setup_inputs) ----------------
#define S_TOK   2048   // tokens (B*S)
#define DMODEL  2048   // D
#define HEXP    512    // H per expert
#define NEXP    32     // E
#define HSH     1024   // shared hidden
#define NPAIR   (S_TOK * 4)   // 8192 (token,expert) pairs, top_k=4
#define NT128   96            // sum ceil(cnt_e/128) <= 8192/128 + 32

// meta layout (ints): 128-row tile table
#define M128_NT  0
#define M128_TE  1
#define M128_TP0 (1 + NT128)
#define M128_TM  (1 + 2 * NT128)
#define META_SIZE (1 + 3 * NT128)

typedef short  s16x8 __attribute__((ext_vector_type(8)));
typedef __bf16 b16x8 __attribute__((ext_vector_type(8)));
typedef float  f32x4 __attribute__((ext_vector_type(4)));

__device__ __forceinline__ f32x4 mfma16x16x32(s16x8 a, s16x8 b, f32x4 c) {
    return __builtin_amdgcn_mfma_f32_16x16x32_bf16(
        __builtin_bit_cast(b16x8, a), __builtin_bit_cast(b16x8, b), c, 0, 0, 0);
}

__device__ __forceinline__ unsigned short f2bf(float f) {
    union { float f; unsigned int u; } v; v.f = f;
    unsigned int u = v.u;
    return (unsigned short)((u + 0x7FFFu + ((u >> 16) & 1u)) >> 16);  // RNE
}

__device__ __forceinline__ float bf2f(unsigned short b) {
    union { unsigned int u; float f; } v; v.u = ((unsigned int)b) << 16;
    return v.f;
}

// async global->LDS, 16B per lane. LDS dest is wave-uniform base + lane*16.
__device__ __forceinline__ void gload16(const unsigned short* g, unsigned short* l) {
    __builtin_amdgcn_global_load_lds(
        (const __attribute__((address_space(1))) void*)(uintptr_t)g,
        (__attribute__((address_space(3))) void*)(uintptr_t)l, 16, 0, 0);
}

// ---- LDS bank swizzle for [row][32-short] GEMM tiles (64B rows) ----
__device__ __forceinline__ int src_col8(int lane) {
    return 8 * ((lane & 3) ^ ((lane >> 3) & 3));
}
__device__ __forceinline__ int frag_ko(int fr, int fq) {
    return 8 * (fq ^ ((fr >> 1) & 3));
}

// ---------------- transpose-convert tile: f32 [K][N] -> bf16 [N][K] ----------------
// LDS [64][64] with XOR-swizzled columns (validated r16: conflicts 3.34M -> 1.11M).
__device__ __forceinline__ void tconv_tile(const float* __restrict__ s,
                                           unsigned short* __restrict__ d,
                                           const int K, const int N,
                                           const int k0, const int n0,
                                           unsigned short* pool)   // >= 4096 shorts
{
    auto T = (unsigned short (*)[64])pool;
    const int tid = threadIdx.x;
    const int n4 = (tid & 15) * 4;
    const int kr = tid >> 4;
    const int wkey = ((n4 >> 2) & 7) << 3;   // shared by rows n4..n4+3
#pragma unroll
    for (int i = 0; i < 4; ++i) {
        const int k = kr + i * 16;
        const float4 v = *reinterpret_cast<const float4*>(s + (size_t)(k0 + k) * N + n0 + n4);
        const int kk = k ^ wkey;
        T[n4 + 0][kk] = f2bf(v.x);
        T[n4 + 1][kk] = f2bf(v.y);
        T[n4 + 2][kk] = f2bf(v.z);
        T[n4 + 3][kk] = f2bf(v.w);
    }
    __syncthreads();
    const int nw = tid >> 2;
    const int kc = (tid & 3) * 16;
    const int rkey = ((nw >> 2) & 7) << 3;
    const uint4 w0 = *reinterpret_cast<const uint4*>(&T[nw][kc ^ rkey]);
    const uint4 w1 = *reinterpret_cast<const uint4*>(&T[nw][(kc + 8) ^ rkey]);
    unsigned short* o = d + (size_t)(n0 + nw) * K + k0 + kc;   // 16B-aligned
    *reinterpret_cast<uint4*>(o)     = w0;
    *reinterpret_cast<uint4*>(o + 8) = w1;
}

// ---------------- router body (one token per block), callable as passenger ---------
__device__ __forceinline__ void router_body(
    int t, const float* __restrict__ x, const float* __restrict__ gate_w,
    const float* __restrict__ expert_bias,
    const float* __restrict__ coef_w, const float* __restrict__ coef_b,
    int* __restrict__ inds, float* __restrict__ scores, float* __restrict__ coefo,
    float* s_logits, float* s_coef)   // LDS: 32 + 2 floats
{
    const int tid = threadIdx.x;
    const int lane = tid & 63;
    const int wave = tid >> 6;
    const float* xr = x + (size_t)t * DMODEL;

    float xv[32];
#pragma unroll
    for (int j = 0; j < 32; ++j) xv[j] = xr[lane + 64 * j];

    for (int i = 0; i < 8; ++i) {
        const int e = wave * 8 + i;
        const float* wr = gate_w + (size_t)e * DMODEL;
        float p = 0.f;
#pragma unroll
        for (int j = 0; j < 32; ++j) p += xv[j] * wr[lane + 64 * j];
#pragma unroll
        for (int o = 32; o > 0; o >>= 1) p += __shfl_xor(p, o);
        if (lane == 0) s_logits[e] = p;
    }
    if (wave == 0) {
        for (int c = 0; c < 2; ++c) {
            const float* wr = coef_w + (size_t)c * DMODEL;
            float p = 0.f;
#pragma unroll
            for (int j = 0; j < 32; ++j) p += xv[j] * wr[lane + 64 * j];
#pragma unroll
            for (int o = 32; o > 0; o >>= 1) p += __shfl_xor(p, o);
            if (lane == 0) s_coef[c] = p;
        }
    }
    __syncthreads();
    if (tid == 0) {
        float routing[NEXP], biased[NEXP];
        for (int e = 0; e < NEXP; ++e) {
            const float r = 1.f / (1.f + expf(-s_logits[e]));
            routing[e] = r;
            biased[e] = r + expert_bias[e];
        }
        int sel[4]; float sc[4]; float ssum = 0.f;
        for (int k = 0; k < 4; ++k) {
            int best = 0; float bv = -1e30f;
            for (int e = 0; e < NEXP; ++e)
                if (biased[e] > bv) { bv = biased[e]; best = e; }  // strict > = lax.top_k
            sel[k] = best; sc[k] = routing[best]; ssum += sc[k];
            biased[best] = -1e30f;
        }
        const float inv = 1.f / (ssum + 1e-20f);
        for (int k = 0; k < 4; ++k) {
            inds[t * 4 + k] = sel[k];
            scores[t * 4 + k] = sc[k] * inv;
        }
        const float l0 = s_coef[0] + coef_b[0];
        const float l1 = s_coef[1] + coef_b[1];
        const float m = fmaxf(l0, l1);
        const float e0 = expf(l0 - m), e1 = expf(l1 - m);
        coefo[t * 2 + 0] = e0 / (e0 + e1);
        coefo[t * 2 + 1] = e1 / (e0 + e1);
    }
}

// ---------------- upfront: wg/wu/sg/su tconv + xcast + router, one dispatch --------
// grid 25600: wg 8192 | wu 8192 | sg 512 | su 512 | xcast 4096 | router 2048 | pad
__global__ __launch_bounds__(256)
void tconv_all_kernel(const float* __restrict__ wg, const float* __restrict__ wu,
                      const float* __restrict__ sg, const float* __restrict__ su,
                      unsigned short* __restrict__ W1, unsigned short* __restrict__ W2,
                      unsigned short* __restrict__ sgb, unsigned short* __restrict__ sub_,
                      const float* __restrict__ x, unsigned short* __restrict__ xb,
                      const float* __restrict__ gate_w,
                      const float* __restrict__ expert_bias,
                      const float* __restrict__ coef_w, const float* __restrict__ coef_b,
                      int* __restrict__ inds, float* __restrict__ scores,
                      float* __restrict__ coefo)
{
    __shared__ unsigned short pool[4096];
    const int bid = blockIdx.x;
    if (bid < 8192) {               // wg [E][2048][512] -> W1 [E][512][2048]
        const int e = bid >> 8, t = bid & 255;
        tconv_tile(wg + (size_t)e * DMODEL * HEXP, W1 + (size_t)e * HEXP * DMODEL,
                   DMODEL, HEXP, ((t >> 3) & 31) * 64, (t & 7) * 64, pool);
    } else if (bid < 16384) {       // wu -> W2
        const int e = (bid - 8192) >> 8, t = bid & 255;
        tconv_tile(wu + (size_t)e * DMODEL * HEXP, W2 + (size_t)e * HEXP * DMODEL,
                   DMODEL, HEXP, ((t >> 3) & 31) * 64, (t & 7) * 64, pool);
    } else if (bid < 16896) {       // sg [2048][1024] -> sgb [1024][2048]
        const int t = bid - 16384;
        tconv_tile(sg, sgb, DMODEL, HSH, (t >> 4) * 64, (t & 15) * 64, pool);
    } else if (bid < 17408) {       // su -> sub_
        const int t = bid - 16896;
        tconv_tile(su, sub_, DMODEL, HSH, (t >> 4) * 64, (t & 15) * 64, pool);
    } else if (bid < 21504) {       // xcast: x f32 -> xb bf16 (1024 elems/block)
        const int idx = bid - 17408;
        const int i = (idx * 256 + (int)threadIdx.x) * 4;
        const float4 v = *reinterpret_cast<const float4*>(x + i);
        ushort4 o;
        o.x = f2bf(v.x); o.y = f2bf(v.y); o.z = f2bf(v.z); o.w = f2bf(v.w);
        *reinterpret_cast<ushort4*>(xb + i) = o;
    } else if (bid < 23552) {       // router: one token per block
        float* fp = reinterpret_cast<float*>(pool);
        router_body(bid - 21504, x, gate_w, expert_bias, coef_w, coef_b,
                    inds, scores, coefo, fp, fp + NEXP);
    }
}

// ---------------- grouping: pair lists + 128-row tile table + token->pos map ----
__global__ __launch_bounds__(1024)
void group_kernel(const int* __restrict__ inds, const float* __restrict__ scores,
                  int* __restrict__ meta, int* __restrict__ pair_token,
                  float* __restrict__ pair_score, int* __restrict__ tok_pos)
{
    __shared__ int cnt[NEXP];
    __shared__ int off_s[NEXP];
    __shared__ int cur[NEXP];
    const int tid = threadIdx.x;
    if (tid < NEXP) cnt[tid] = 0;
    __syncthreads();
    for (int i = tid; i < NPAIR; i += 1024) atomicAdd(&cnt[inds[i]], 1);
    __syncthreads();
    if (tid == 0) {
        int run = 0, nt1 = 0;
        for (int e = 0; e < NEXP; ++e) {
            off_s[e] = run;
            const int c = cnt[e];
            for (int m0 = 0; m0 < c; m0 += 128) {
                meta[M128_TE + nt1] = e;
                meta[M128_TP0 + nt1] = run + m0;
                meta[M128_TM + nt1] = (c - m0 < 128) ? (c - m0) : 128;
                ++nt1;
            }
            run += c;
        }
        meta[M128_NT] = nt1;
    }
    __syncthreads();
    if (tid < NEXP) cur[tid] = off_s[tid];
    __syncthreads();
    for (int i = tid; i < NPAIR; i += 1024) {
        const int e = inds[i];
        const int pos = atomicAdd(&cur[e], 1);
        pair_token[pos] = i >> 2;
        pair_score[pos] = scores[i];
        tok_pos[i] = pos;
    }
}

// ---------------- gate/up GEMM 128x128 + passenger tconv(wd -> wdb, sd -> sdb) ----
// grid 9728:
//   [0, 8*NT128)        expert tile (tt=bid>>3; r=bid&7: mat=r>>2, n0=(r&3)*128)
//   [8*NT128, +256)     shared tile
//   rest                passenger tconv (wd 8192 tiles, sd 512 tiles)
__global__ __launch_bounds__(256, 4)
void gu128_kernel(const unsigned short* __restrict__ xb,
                  const unsigned short* __restrict__ W1,
                  const unsigned short* __restrict__ W2,
                  const int* __restrict__ meta, const int* __restrict__ pair_token,
                  const unsigned short* __restrict__ sgb,
                  const unsigned short* __restrict__ sub_,
                  unsigned short* __restrict__ hexp, unsigned short* __restrict__ uexp,
                  unsigned short* __restrict__ shh, unsigned short* __restrict__ shu,
                  const float* __restrict__ wd, unsigned short* __restrict__ wdb,
                  const float* __restrict__ sd, unsigned short* __restrict__ sdb)
{
    constexpr int NT = DMODEL / 32;
    __shared__ unsigned short pool[16384];   // 32 KB (GEMM dbuf or tconv tile)
    auto Al = (unsigned short (*)[128][32])(pool);
    auto Bl = (unsigned short (*)[128][32])(pool + 8192);

    const int bid = blockIdx.x;
    const int tid = threadIdx.x;
    const int lane = tid & 63;
    const int wave = tid >> 6;

    if (bid >= 8 * NT128 + 256) {   // ---- passenger tconv role ----
        const int idx = bid - (8 * NT128 + 256);
        if (idx < 8192) {           // wd [E][512][2048] -> wdb [E][2048][512]
            const int e = idx >> 8, t = idx & 255;
            tconv_tile(wd + (size_t)e * HEXP * DMODEL, wdb + (size_t)e * DMODEL * HEXP,
                       HEXP, DMODEL, (t >> 5) * 64, (t & 31) * 64, pool);
        } else {                    // sd [1024][2048] -> sdb [2048][1024]
            const int t = idx - 8192;
            tconv_tile(sd, sdb, HSH, DMODEL, (t >> 5) * 64, (t & 31) * 64, pool);
        }
        return;
    }

    const int fr = lane & 15, fq = lane >> 4;
    const int ko = frag_ko(fr, fq);
    const int sub = lane >> 2;
    const int col8 = src_col8(lane);
    const int wm = wave >> 1, wn = wave & 1;
    const f32x4 zero4 = {0.f, 0.f, 0.f, 0.f};

    const bool EXPERT = bid < 8 * NT128;
    int p0, mval, n0, NB;
    const unsigned short* B;
    unsigned short* obuf;
    int tok0, tok1;
    const int arow0 = wave * 32 + sub;
    if (EXPERT) {
        const int tt = bid >> 3;
        if (tt >= meta[M128_NT]) return;
        const int e = meta[M128_TE + tt];
        p0 = meta[M128_TP0 + tt];
        mval = meta[M128_TM + tt];
        const int r = bid & 7;
        const int mat = r >> 2;
        n0 = (r & 3) * 128;
        NB = HEXP;
        B = (mat ? W2 : W1) + (size_t)e * HEXP * DMODEL;
        obuf = mat ? uexp : hexp;
        int q0 = p0 + arow0;      if (q0 > NPAIR - 1) q0 = NPAIR - 1;
        int q1 = p0 + arow0 + 16; if (q1 > NPAIR - 1) q1 = NPAIR - 1;
        tok0 = pair_token[q0];
        tok1 = pair_token[q1];
    } else {
        const int idx = bid - 8 * NT128;   // 256 blocks: 16m x 8n x 2mats
        const int mat = idx & 1;
        n0 = ((idx >> 1) & 7) * 128;
        p0 = (idx >> 4) * 128;
        mval = 128;
        NB = HSH;
        B = mat ? sub_ : sgb;
        obuf = mat ? shu : shh;
        tok0 = p0 + arow0;
        tok1 = p0 + arow0 + 16;
    }

    const unsigned short* asrc0 = xb + (size_t)tok0 * DMODEL + col8;
    const unsigned short* asrc1 = xb + (size_t)tok1 * DMODEL + col8;
    const unsigned short* bsrc0 = B + (size_t)(n0 + arow0) * DMODEL + col8;
    const unsigned short* bsrc1 = B + (size_t)(n0 + arow0 + 16) * DMODEL + col8;

    auto stage = [&](int buf, int k0) {
        gload16(asrc0 + k0, &Al[buf][wave * 32][0]);
        gload16(asrc1 + k0, &Al[buf][wave * 32 + 16][0]);
        gload16(bsrc0 + k0, &Bl[buf][wave * 32][0]);
        gload16(bsrc1 + k0, &Bl[buf][wave * 32 + 16][0]);
    };

    f32x4 acc[4][4];
#pragma unroll
    for (int m = 0; m < 4; ++m)
#pragma unroll
        for (int n = 0; n < 4; ++n) acc[m][n] = zero4;

    auto compute = [&](int buf) {
        s16x8 af[4], bf[4];
#pragma unroll
        for (int m = 0; m < 4; ++m)
            af[m] = *reinterpret_cast<const s16x8*>(&Al[buf][wm * 64 + m * 16 + fr][ko]);
#pragma unroll
        for (int n = 0; n < 4; ++n)
            bf[n] = *reinterpret_cast<const s16x8*>(&Bl[buf][wn * 64 + n * 16 + fr][ko]);
#pragma unroll
        for (int m = 0; m < 4; ++m)
#pragma unroll
            for (int n = 0; n < 4; ++n)
                acc[m][n] = mfma16x16x32(af[m], bf[n], acc[m][n]);
    };

    stage(0, 0);
    __syncthreads();
#pragma unroll 1
    for (int t = 0; t < NT; ++t) {
        const int cur = t & 1;
        if (t + 1 < NT) stage(cur ^ 1, (t + 1) * 32);
        compute(cur);
        __syncthreads();
    }

#pragma unroll
    for (int m = 0; m < 4; ++m)
#pragma unroll
        for (int n = 0; n < 4; ++n) {
            const int col = n0 + wn * 64 + n * 16 + fr;
#pragma unroll
            for (int r = 0; r < 4; ++r) {
                const int rt = wm * 64 + m * 16 + fq * 4 + r;
                if (rt < mval)
                    obuf[(size_t)(p0 + rt) * NB + col] = f2bf(acc[m][n][r]);
            }
        }
}

// ---------------- swiglu combine: act = silu(h)*u (expert + shared) ----------------
__global__ __launch_bounds__(256)
void swiglu_kernel(const unsigned short* __restrict__ hexp,
                   const unsigned short* __restrict__ uexp,
                   unsigned short* __restrict__ act,
                   const unsigned short* __restrict__ shh,
                   const unsigned short* __restrict__ shu,
                   unsigned short* __restrict__ shact)
{
    constexpr size_t NE = (size_t)NPAIR * HEXP;   // 4194304
    const size_t i = ((size_t)blockIdx.x * 256 + threadIdx.x) * 8;
    const unsigned short *hp, *up;
    unsigned short* ap;
    size_t j;
    if (i < NE) { hp = hexp; up = uexp; ap = act; j = i; }
    else        { hp = shh;  up = shu;  ap = shact; j = i - NE; }
    const uint4 hv = *reinterpret_cast<const uint4*>(hp + j);
    const uint4 uv = *reinterpret_cast<const uint4*>(up + j);
    const unsigned short* hu = reinterpret_cast<const unsigned short*>(&hv);
    const unsigned short* uu = reinterpret_cast<const unsigned short*>(&uv);
    ushort4 o[2];
    unsigned short* ou = reinterpret_cast<unsigned short*>(o);
#pragma unroll
    for (int k = 0; k < 8; ++k) {
        const float h = bf2f(hu[k]);
        const float u = bf2f(uu[k]);
        ou[k] = f2bf(h / (1.f + __expf(-h)) * u);
    }
    *reinterpret_cast<uint4*>(ap + j) = *reinterpret_cast<const uint4*>(o);
}

// ---------------- down GEMM 128x128: expert(->ypair) + shared(->sdown) -------------
__global__ __launch_bounds__(256, 4)
void down128_kernel(const unsigned short* __restrict__ act,
                    const unsigned short* __restrict__ shact,
                    const unsigned short* __restrict__ wdb,
                    const unsigned short* __restrict__ sdb,
                    unsigned short* __restrict__ ypair,
                    float* __restrict__ sdown,
                    const int* __restrict__ meta,
                    const float* __restrict__ pair_score)
{
    __shared__ unsigned short Al[2][128][32];
    __shared__ unsigned short Bl[2][128][32];

    const int bid = blockIdx.x;
    const int tid = threadIdx.x;
    const int lane = tid & 63;
    const int wave = tid >> 6;
    const int fr = lane & 15, fq = lane >> 4;
    const int ko = frag_ko(fr, fq);
    const int sub = lane >> 2;
    const int col8 = src_col8(lane);
    const int wm = wave >> 1, wn = wave & 1;
    const f32x4 zero4 = {0.f, 0.f, 0.f, 0.f};

    const bool EXPERT = bid < 16 * NT128;
    int p0, mval, n0, KA;
    const unsigned short *Asrc, *B;
    if (EXPERT) {
        const int tt = bid >> 4;
        if (tt >= meta[M128_NT]) return;
        const int e = meta[M128_TE + tt];
        p0 = meta[M128_TP0 + tt];
        mval = meta[M128_TM + tt];
        n0 = (bid & 15) * 128;
        KA = HEXP;
        Asrc = act;
        B = wdb + (size_t)e * DMODEL * HEXP;
    } else {
        const int idx = bid - 16 * NT128;   // 256 blocks: 16m x 16n
        p0 = (idx >> 4) * 128;
        mval = 128;
        n0 = (idx & 15) * 128;
        KA = HSH;
        Asrc = shact;
        B = sdb;
    }
    const int NT = KA / 32;

    const int arow0 = wave * 32 + sub;
    const unsigned short* asrc0 = Asrc + (size_t)(p0 + arow0) * KA + col8;
    const unsigned short* asrc1 = Asrc + (size_t)(p0 + arow0 + 16) * KA + col8;
    const unsigned short* bsrc0 = B + (size_t)(n0 + arow0) * KA + col8;
    const unsigned short* bsrc1 = B + (size_t)(n0 + arow0 + 16) * KA + col8;

    auto stage = [&](int buf, int k0) {
        gload16(asrc0 + k0, &Al[buf][wave * 32][0]);
        gload16(asrc1 + k0, &Al[buf][wave * 32 + 16][0]);
        gload16(bsrc0 + k0, &Bl[buf][wave * 32][0]);
        gload16(bsrc1 + k0, &Bl[buf][wave * 32 + 16][0]);
    };

    f32x4 acc[4][4];
#pragma unroll
    for (int m = 0; m < 4; ++m)
#pragma unroll
        for (int n = 0; n < 4; ++n) acc[m][n] = zero4;

    auto compute = [&](int buf) {
        s16x8 af[4], bf[4];
#pragma unroll
        for (int m = 0; m < 4; ++m)
            af[m] = *reinterpret_cast<const s16x8*>(&Al[buf][wm * 64 + m * 16 + fr][ko]);
#pragma unroll
        for (int n = 0; n < 4; ++n)
            bf[n] = *reinterpret_cast<const s16x8*>(&Bl[buf][wn * 64 + n * 16 + fr][ko]);
#pragma unroll
        for (int m = 0; m < 4; ++m)
#pragma unroll
            for (int n = 0; n < 4; ++n)
                acc[m][n] = mfma16x16x32(af[m], bf[n], acc[m][n]);
    };

    stage(0, 0);
    __syncthreads();
#pragma unroll 1
    for (int t = 0; t < NT; ++t) {
        const int cur = t & 1;
        if (t + 1 < NT) stage(cur ^ 1, (t + 1) * 32);
        compute(cur);
        __syncthreads();
    }

#pragma unroll
    for (int m = 0; m < 4; ++m)
#pragma unroll
        for (int n = 0; n < 4; ++n) {
            const int col = n0 + wn * 64 + n * 16 + fr;
#pragma unroll
            for (int r = 0; r < 4; ++r) {
                const int rt = wm * 64 + m * 16 + fq * 4 + r;
                if (rt < mval) {
                    if (EXPERT) {
                        const int p = p0 + rt;
                        ypair[(size_t)p * DMODEL + col] = f2bf(acc[m][n][r] * pair_score[p]);
                    } else {
                        sdown[(size_t)(p0 + rt) * DMODEL + col] = acc[m][n][r];
                    }
                }
            }
        }
}

// ---------------- final: out = (sum_k ypair[pos_k])*c0 + sdown*c1 ----------------
__global__ __launch_bounds__(256)
void final_kernel(const unsigned short* __restrict__ ypair,
                  const float* __restrict__ sdown,
                  const float* __restrict__ coef, const int* __restrict__ tok_pos,
                  float* __restrict__ out)
{
    const int row = blockIdx.x;
    const int col = threadIdx.x * 8;
    float acc[8] = {0.f, 0.f, 0.f, 0.f, 0.f, 0.f, 0.f, 0.f};
#pragma unroll
    for (int k = 0; k < 4; ++k) {
        const int pos = tok_pos[row * 4 + k];
        const uint4 v = *reinterpret_cast<const uint4*>(ypair + (size_t)pos * DMODEL + col);
        const unsigned short* u = reinterpret_cast<const unsigned short*>(&v);
#pragma unroll
        for (int j = 0; j < 8; ++j) acc[j] += bf2f(u[j]);
    }
    const float c0 = coef[row * 2 + 0];
    const float c1 = coef[row * 2 + 1];
    const float* sd = sdown + (size_t)row * DMODEL + col;
    const float4 s0 = *reinterpret_cast<const float4*>(sd);
    const float4 s1 = *reinterpret_cast<const float4*>(sd + 4);
    float4 o0, o1;
    o0.x = acc[0] * c0 + s0.x * c1; o0.y = acc[1] * c0 + s0.y * c1;
    o0.z = acc[2] * c0 + s0.z * c1; o0.w = acc[3] * c0 + s0.w * c1;
    o1.x = acc[4] * c0 + s1.x * c1; o1.y = acc[5] * c0 + s1.y * c1;
    o1.z = acc[6] * c0 + s1.z * c1; o1.w = acc[7] * c0 + s1.w * c1;
    float* op = out + (size_t)row * DMODEL + col;
    *reinterpret_cast<float4*>(op) = o0;
    *reinterpret_cast<float4*>(op + 4) = o1;
}

// ---------------- launch ----------------
extern "C" void kernel_launch(void* const* d_in, const int* in_sizes, int n_in,
                              void* d_out, int out_size, void* d_ws, size_t ws_size,
                              hipStream_t stream)
{
    const float* x           = (const float*)d_in[0];
    const float* gate_w      = (const float*)d_in[1];
    const float* expert_bias = (const float*)d_in[2];
    const float* wg          = (const float*)d_in[3];
    const float* wu          = (const float*)d_in[4];
    const float* wd          = (const float*)d_in[5];
    const float* sg          = (const float*)d_in[6];
    const float* su          = (const float*)d_in[7];
    const float* sd          = (const float*)d_in[8];
    const float* coef_w      = (const float*)d_in[9];
    const float* coef_b      = (const float*)d_in[10];
    float* out = (float*)d_out;

    char* ws = (char*)d_ws;
    size_t off = 0;
    auto take = [&](size_t bytes) {
        char* p = ws + off;
        off = (off + bytes + 255) & ~(size_t)255;
        return p;
    };
    int*   inds     = (int*)  take((size_t)S_TOK * 4 * sizeof(int));
    float* scores   = (float*)take((size_t)S_TOK * 4 * sizeof(float));
    float* coefp    = (float*)take((size_t)S_TOK * 2 * sizeof(float));
    int*   meta     = (int*)  take((size_t)META_SIZE * sizeof(int));
    int*   pair_tok = (int*)  take((size_t)NPAIR * sizeof(int));
    float* pair_sc  = (float*)take((size_t)NPAIR * sizeof(float));
    int*   tok_pos  = (int*)  take((size_t)NPAIR * sizeof(int));
    unsigned short* xb    = (unsigned short*)take((size_t)S_TOK * DMODEL * 2);
    unsigned short* act   = (unsigned short*)take((size_t)NPAIR * HEXP * 2);
    unsigned short* hexp  = (unsigned short*)take((size_t)NPAIR * HEXP * 2);
    unsigned short* uexp  = (unsigned short*)take((size_t)NPAIR * HEXP * 2);
    unsigned short* shact = (unsigned short*)take((size_t)S_TOK * HSH * 2);
    unsigned short* shh   = (unsigned short*)take((size_t)S_TOK * HSH * 2);
    unsigned short* shu   = (unsigned short*)take((size_t)S_TOK * HSH * 2);
    unsigned short* ypair = (unsigned short*)take((size_t)NPAIR * DMODEL * 2);  // 33.5MB
    float*          sdown = (float*)take((size_t)S_TOK * DMODEL * 4);           // 16.8MB
    unsigned short* sgb   = (unsigned short*)take((size_t)HSH * DMODEL * 2);
    unsigned short* sub_  = (unsigned short*)take((size_t)HSH * DMODEL * 2);
    unsigned short* sdb   = (unsigned short*)take((size_t)DMODEL * HSH * 2);
    unsigned short* W1    = (unsigned short*)take((size_t)NEXP * DMODEL * HEXP * 2); // 67MB
    unsigned short* W2    = (unsigned short*)take((size_t)NEXP * DMODEL * HEXP * 2); // 67MB
    unsigned short* wdb   = (unsigned short*)take((size_t)NEXP * DMODEL * HEXP * 2); // 67MB
    (void)ws_size; (void)in_sizes; (void)n_in; (void)out_size;

    // weights/x conversions + router, single dispatch (router blocks at the tail)
    tconv_all_kernel<<<23552, 256, 0, stream>>>(
        wg, wu, sg, su, W1, W2, sgb, sub_, x, xb,
        gate_w, expert_bias, coef_w, coef_b, inds, scores, coefp);

    group_kernel<<<1, 1024, 0, stream>>>(inds, scores, meta, pair_tok, pair_sc, tok_pos);

    // gate/up GEMMs (768 expert + 256 shared) + 8704 passenger tconv blocks
    gu128_kernel<<<8 * NT128 + 256 + 8704, 256, 0, stream>>>(
        xb, W1, W2, meta, pair_tok, sgb, sub_, hexp, uexp, shh, shu,
        wd, wdb, sd, sdb);

    // act = silu(h)*u for expert and shared (6.29M elems, 8/thread)
    swiglu_kernel<<<3072, 256, 0, stream>>>(hexp, uexp, act, shh, shu, shact);

    // down GEMMs: expert (1536 -> ypair) + shared (256 -> sdown)
    down128_kernel<<<16 * NT128 + 256, 256, 0, stream>>>(
        act, shact, wdb, sdb, ypair, sdown, meta, pair_sc);

    // final combine (each out element written exactly once)
    final_kernel<<<S_TOK, 256, 0, stream>>>(ypair, sdown, coefp, tok_pos, out);
}